// Round 2
// baseline (1987.581 us; speedup 1.0000x reference)
//
#include <hip/hip_runtime.h>
#include <stdint.h>

typedef __bf16 bf16_t;
typedef __bf16 bf16x8 __attribute__((ext_vector_type(8)));
typedef __bf16 bf16x4 __attribute__((ext_vector_type(4)));
typedef float  f32x4  __attribute__((ext_vector_type(4)));

#define BMT 128
#define BNT 128
#define BKT 32
#define LDK 40   // padded LDS row stride (elements)

enum { M_PLAIN=0, M_BIAS, M_BIAS_RES, M_BIAS_RELU, M_SCORES, M_EXPERT };

// C[M,N] = A[M,K] @ Bt[N,K]^T  (+ epilogue per MODE). Batched via grid.z strides.
// A, Bt are bf16; biases/residual/gates are fp32; output bf16 (Ob) or fp32 (Of).
template<int MODE>
__global__ __launch_bounds__(256)
void gemm_nt(const bf16_t* __restrict__ A, const bf16_t* __restrict__ Bt,
             bf16_t* __restrict__ Ob, float* __restrict__ Of,
             const float* __restrict__ bias, const float* __restrict__ res,
             const float* __restrict__ gates, int gate_e, int einit, float scale,
             int M, int N, int K, long sA, long sB, long sC)
{
    __shared__ bf16_t As[BMT * LDK];
    __shared__ bf16_t Bs[BNT * LDK];

    const int z = blockIdx.z;
    A  += (long)z * sA;
    Bt += (long)z * sB;
    const long cbase = (long)z * sC;

    const int tid  = threadIdx.x;
    const int wave = tid >> 6, lane = tid & 63;
    const int l16  = lane & 15, quad = lane >> 4;
    const int m0 = blockIdx.y * BMT, n0 = blockIdx.x * BNT;
    const int wr = wave >> 1, wc = wave & 1;   // 2x2 waves, each 64x64

    f32x4 acc[4][4];
    #pragma unroll
    for (int i = 0; i < 4; i++)
        #pragma unroll
        for (int j = 0; j < 4; j++)
            acc[i][j] = f32x4{0.f, 0.f, 0.f, 0.f};

    const int srow = tid >> 1;          // 0..127
    const int scol = (tid & 1) * 16;    // 0 or 16

    const bf16_t* Aptr = A  + (long)(m0 + srow) * K + scol;
    const bf16_t* Bptr = Bt + (long)(n0 + srow) * K + scol;

    for (int k0 = 0; k0 < K; k0 += BKT) {
        uint4 av0 = *(const uint4*)(Aptr + k0);
        uint4 av1 = *(const uint4*)(Aptr + k0 + 8);
        uint4 bv0 = *(const uint4*)(Bptr + k0);
        uint4 bv1 = *(const uint4*)(Bptr + k0 + 8);
        __syncthreads();
        *(uint4*)&As[srow * LDK + scol]     = av0;
        *(uint4*)&As[srow * LDK + scol + 8] = av1;
        *(uint4*)&Bs[srow * LDK + scol]     = bv0;
        *(uint4*)&Bs[srow * LDK + scol + 8] = bv1;
        __syncthreads();

        bf16x8 af[4], bfr[4];
        #pragma unroll
        for (int i = 0; i < 4; i++)
            af[i] = *(const bf16x8*)&As[(wr * 64 + i * 16 + l16) * LDK + quad * 8];
        #pragma unroll
        for (int j = 0; j < 4; j++)
            bfr[j] = *(const bf16x8*)&Bs[(wc * 64 + j * 16 + l16) * LDK + quad * 8];

        #pragma unroll
        for (int i = 0; i < 4; i++)
            #pragma unroll
            for (int j = 0; j < 4; j++)
                acc[i][j] = __builtin_amdgcn_mfma_f32_16x16x32_bf16(af[i], bfr[j], acc[i][j], 0, 0, 0);
    }

    // epilogue: D[row][col], col = lane&15, row = quad*4 + r  (m89/m91 layout)
    #pragma unroll
    for (int i = 0; i < 4; i++) {
        const int row = m0 + wr * 64 + i * 16 + quad * 4;
        #pragma unroll
        for (int j = 0; j < 4; j++) {
            const int col = n0 + wc * 64 + j * 16 + l16;
            #pragma unroll
            for (int r = 0; r < 4; r++) {
                const long idx = cbase + (long)(row + r) * N + col;
                const float vv = acc[i][j][r];
                if (MODE == M_SCORES) {
                    Of[idx] = vv * scale;
                } else if (MODE == M_PLAIN) {
                    Ob[idx] = (bf16_t)vv;
                } else if (MODE == M_BIAS) {
                    Ob[idx] = (bf16_t)(vv + bias[col]);
                } else if (MODE == M_BIAS_RES) {
                    Ob[idx] = (bf16_t)(vv + bias[col] + res[idx]);
                } else if (MODE == M_BIAS_RELU) {
                    float t = vv + bias[col];
                    Ob[idx] = (bf16_t)(t > 0.f ? t : 0.f);
                } else if (MODE == M_EXPERT) {
                    float g = gates[(row + r) * 8 + gate_e];
                    float t = g * (vv + bias[col]);
                    Of[idx] = (einit ? 0.f : Of[idx]) + t;
                }
            }
        }
    }
}

// out[C,R] = bf16(in[R,C]^T), input fp32 or bf16, batched via grid.z
template<typename TIN>
__global__ __launch_bounds__(256)
void transpose_to_bf16(const TIN* __restrict__ in, bf16_t* __restrict__ out,
                       int R, int C, long sIn, long sOut)
{
    __shared__ bf16_t tile[32][33];
    const int z = blockIdx.z;
    in  += (long)z * sIn;
    out += (long)z * sOut;
    const int c0 = blockIdx.x * 32, r0 = blockIdx.y * 32;
    const int tx = threadIdx.x, ty = threadIdx.y;
    #pragma unroll
    for (int i = ty; i < 32; i += 8)
        tile[i][tx] = (bf16_t)(float)in[(long)(r0 + i) * C + c0 + tx];
    __syncthreads();
    #pragma unroll
    for (int i = ty; i < 32; i += 8)
        out[(long)(c0 + i) * R + r0 + tx] = tile[tx][i];
}

// elementwise fp32 -> bf16, 4/thread
__global__ __launch_bounds__(256)
void convert_f32_bf16(const float* __restrict__ in, bf16_t* __restrict__ out, int n)
{
    const int i = (blockIdx.x * 256 + threadIdx.x) * 4;
    if (i >= n) return;
    const float4 v = *(const float4*)(in + i);
    bf16x4 o;
    o[0] = (bf16_t)v.x; o[1] = (bf16_t)v.y; o[2] = (bf16_t)v.z; o[3] = (bf16_t)v.w;
    *(bf16x4*)(out + i) = o;
}

// row softmax over 1024 fp32 cols -> bf16
__global__ __launch_bounds__(256)
void softmax_rows(const float* __restrict__ Sc, bf16_t* __restrict__ P)
{
    const int row = blockIdx.x, tid = threadIdx.x, wave = tid >> 6, lane = tid & 63;
    const float* sr = Sc + (long)row * 1024;
    bf16_t* pr = P + (long)row * 1024;
    float v[4];
    float mx = -3.4e38f;
    #pragma unroll
    for (int i = 0; i < 4; i++) { v[i] = sr[tid + 256 * i]; mx = fmaxf(mx, v[i]); }
    #pragma unroll
    for (int off = 32; off; off >>= 1) mx = fmaxf(mx, __shfl_down(mx, off));
    __shared__ float sm[4], ss[4];
    if (lane == 0) sm[wave] = mx;
    __syncthreads();
    mx = fmaxf(fmaxf(sm[0], sm[1]), fmaxf(sm[2], sm[3]));
    float sum = 0.f;
    #pragma unroll
    for (int i = 0; i < 4; i++) { v[i] = __expf(v[i] - mx); sum += v[i]; }
    #pragma unroll
    for (int off = 32; off; off >>= 1) sum += __shfl_down(sum, off);
    if (lane == 0) ss[wave] = sum;
    __syncthreads();
    const float inv = 1.f / (ss[0] + ss[1] + ss[2] + ss[3]);
    #pragma unroll
    for (int i = 0; i < 4; i++) pr[tid + 256 * i] = (bf16_t)(v[i] * inv);
}

// gates[t][e] = softmax_e(x2[t,:] @ Wg + bg), one wave per token; Wg/bg fp32
__global__ __launch_bounds__(256)
void gates_kernel(const bf16_t* __restrict__ x2, const float* __restrict__ Wg,
                  const float* __restrict__ bg, float* __restrict__ gates, int H)
{
    const int wave = threadIdx.x >> 6, lane = threadIdx.x & 63;
    const int t = blockIdx.x * 4 + wave;
    const bf16_t* xr = x2 + (long)t * H;
    float acc[8] = {0.f, 0.f, 0.f, 0.f, 0.f, 0.f, 0.f, 0.f};
    for (int h = lane; h < H; h += 64) {
        const float xv = (float)xr[h];
        const float4 w0 = *(const float4*)(Wg + h * 8);
        const float4 w1 = *(const float4*)(Wg + h * 8 + 4);
        acc[0] += xv * w0.x; acc[1] += xv * w0.y; acc[2] += xv * w0.z; acc[3] += xv * w0.w;
        acc[4] += xv * w1.x; acc[5] += xv * w1.y; acc[6] += xv * w1.z; acc[7] += xv * w1.w;
    }
    #pragma unroll
    for (int off = 32; off; off >>= 1)
        #pragma unroll
        for (int e = 0; e < 8; e++) acc[e] += __shfl_down(acc[e], off);
    if (lane == 0) {
        float mx = -3.4e38f;
        #pragma unroll
        for (int e = 0; e < 8; e++) { acc[e] += bg[e]; mx = fmaxf(mx, acc[e]); }
        float s = 0.f;
        #pragma unroll
        for (int e = 0; e < 8; e++) { acc[e] = __expf(acc[e] - mx); s += acc[e]; }
        const float inv = 1.f / s;
        #pragma unroll
        for (int e = 0; e < 8; e++) gates[t * 8 + e] = acc[e] * inv;
    }
}

// out = fp32(x2) + y, 4 elems/thread
__global__ __launch_bounds__(256)
void final_add(const bf16_t* __restrict__ x2, const float* __restrict__ y,
               float* __restrict__ out, int n)
{
    const int i = (blockIdx.x * 256 + threadIdx.x) * 4;
    if (i >= n) return;
    const bf16x4 xv = *(const bf16x4*)(x2 + i);
    const float4 yv = *(const float4*)(y + i);
    float4 o;
    o.x = (float)xv[0] + yv.x;
    o.y = (float)xv[1] + yv.y;
    o.z = (float)xv[2] + yv.z;
    o.w = (float)xv[3] + yv.w;
    *(float4*)(out + i) = o;
}

extern "C" void kernel_launch(void* const* d_in, const int* in_sizes, int n_in,
                              void* d_out, int out_size, void* d_ws, size_t ws_size,
                              hipStream_t stream)
{
    const int Bb = 4, S = 1024, H = 1024, D = 4096, T = Bb * S;

    const float* x  = (const float*)d_in[0];
    const float* Wq = (const float*)d_in[1];
    const float* bq = (const float*)d_in[2];
    const float* Wk = (const float*)d_in[3];
    const float* bk = (const float*)d_in[4];
    const float* Wv = (const float*)d_in[5];
    const float* bv = (const float*)d_in[6];
    const float* Wo = (const float*)d_in[7];
    const float* bo = (const float*)d_in[8];
    const float* Wg = (const float*)d_in[9];
    const float* bg = (const float*)d_in[10];
    const float* W1 = (const float*)d_in[11];
    const float* b1 = (const float*)d_in[12];
    const float* W2 = (const float*)d_in[13];
    const float* b2 = (const float*)d_in[14];
    float* out = (float*)d_out;

    char* w = (char*)d_ws;
    auto alloc = [&](size_t bytes) { char* p = w; w += (bytes + 255) & ~(size_t)255; return p; };

    bf16_t* x_bf   = (bf16_t*)alloc((size_t)T * H * 2);
    bf16_t* WqT    = (bf16_t*)alloc((size_t)H * H * 2);
    bf16_t* WkT    = (bf16_t*)alloc((size_t)H * H * 2);
    bf16_t* WvT    = (bf16_t*)alloc((size_t)H * H * 2);
    bf16_t* WoT    = (bf16_t*)alloc((size_t)H * H * 2);
    bf16_t* q      = (bf16_t*)alloc((size_t)T * H * 2);
    bf16_t* k      = (bf16_t*)alloc((size_t)T * H * 2);
    bf16_t* v      = (bf16_t*)alloc((size_t)T * H * 2);
    bf16_t* vT     = (bf16_t*)alloc((size_t)T * H * 2);
    float*  scores = (float*) alloc((size_t)Bb * S * S * 4);
    float*  gates  = (float*) alloc((size_t)T * 8 * 4);
    bf16_t* W1T    = (bf16_t*)alloc((size_t)D * H * 2);
    bf16_t* W2T    = (bf16_t*)alloc((size_t)H * D * 2);
    bf16_t* hmid   = (bf16_t*)alloc((size_t)T * D * 2);
    float*  y      = (float*) alloc((size_t)T * H * 4);
    bf16_t* attn = q;  // q dead after scores
    bf16_t* a    = k;  // k dead after scores
    bf16_t* x2   = v;  // v dead after vT

    const dim3 tb(32, 8);

    // --- convert + transpose params ---
    convert_f32_bf16<<<(T * H) / 1024, 256, 0, stream>>>(x, x_bf, T * H);
    transpose_to_bf16<float><<<dim3(32, 32, 1), tb, 0, stream>>>(Wq, WqT, H, H, 0, 0);
    transpose_to_bf16<float><<<dim3(32, 32, 1), tb, 0, stream>>>(Wk, WkT, H, H, 0, 0);
    transpose_to_bf16<float><<<dim3(32, 32, 1), tb, 0, stream>>>(Wv, WvT, H, H, 0, 0);
    transpose_to_bf16<float><<<dim3(32, 32, 1), tb, 0, stream>>>(Wo, WoT, H, H, 0, 0);

    // --- attention ---
    gemm_nt<M_BIAS><<<dim3(8, 32, 1), 256, 0, stream>>>(x_bf, WqT, q, nullptr, bq, nullptr, nullptr, 0, 0, 0.f, T, H, H, 0, 0, 0);
    gemm_nt<M_BIAS><<<dim3(8, 32, 1), 256, 0, stream>>>(x_bf, WkT, k, nullptr, bk, nullptr, nullptr, 0, 0, 0.f, T, H, H, 0, 0, 0);
    gemm_nt<M_BIAS><<<dim3(8, 32, 1), 256, 0, stream>>>(x_bf, WvT, v, nullptr, bv, nullptr, nullptr, 0, 0, 0.f, T, H, H, 0, 0, 0);

    transpose_to_bf16<bf16_t><<<dim3(32, 32, 4), tb, 0, stream>>>(v, vT, S, H, (long)S * H, (long)H * S);

    gemm_nt<M_SCORES><<<dim3(8, 8, 4), 256, 0, stream>>>(q, k, nullptr, scores, nullptr, nullptr, nullptr, 0, 0, 0.03125f,
                                                         S, S, H, (long)S * H, (long)S * H, (long)S * S);
    softmax_rows<<<Bb * S, 256, 0, stream>>>(scores, attn);

    gemm_nt<M_PLAIN><<<dim3(8, 8, 4), 256, 0, stream>>>(attn, vT, a, nullptr, nullptr, nullptr, nullptr, 0, 0, 0.f,
                                                        S, H, S, (long)S * S, (long)H * S, (long)S * H);
    gemm_nt<M_BIAS_RES><<<dim3(8, 32, 1), 256, 0, stream>>>(a, WoT, x2, nullptr, bo, x, nullptr, 0, 0, 0.f, T, H, H, 0, 0, 0);

    // --- soft-MoE ---
    gates_kernel<<<T / 4, 256, 0, stream>>>(x2, Wg, bg, gates, H);

    for (int e = 0; e < 8; e++) {
        transpose_to_bf16<float><<<dim3(128, 32, 1), tb, 0, stream>>>(W1 + (long)e * H * D, W1T, H, D, 0, 0);
        gemm_nt<M_BIAS_RELU><<<dim3(32, 32, 1), 256, 0, stream>>>(x2, W1T, hmid, nullptr, b1 + (long)e * D,
                                                                  nullptr, nullptr, 0, 0, 0.f, T, D, H, 0, 0, 0);
        transpose_to_bf16<float><<<dim3(32, 128, 1), tb, 0, stream>>>(W2 + (long)e * D * H, W2T, D, H, 0, 0);
        gemm_nt<M_EXPERT><<<dim3(8, 32, 1), 256, 0, stream>>>(hmid, W2T, nullptr, y, b2 + (long)e * H,
                                                              nullptr, gates, e, (e == 0) ? 1 : 0, 0.f, T, H, D, 0, 0, 0);
    }

    final_add<<<(T * H) / 1024, 256, 0, stream>>>(x2, y, out, T * H);
}

// Round 4
// 1827.180 us; speedup vs baseline: 1.0878x; 1.0878x over previous
//
#include <hip/hip_runtime.h>
#include <stdint.h>

typedef __bf16 bf16_t;
typedef __bf16 bf16x8 __attribute__((ext_vector_type(8)));
typedef __bf16 bf16x4 __attribute__((ext_vector_type(4)));
typedef float  f32x4  __attribute__((ext_vector_type(4)));

enum { M_PLAIN=0, M_BIAS, M_BIAS_RES, M_SCORES, M_W1, M_PART };

// async 16B global->LDS. LDS ptr must be wave-uniform; HW adds lane*16.
__device__ __forceinline__ void gll16(const bf16_t* g, bf16_t* l) {
    __builtin_amdgcn_global_load_lds(
        (const __attribute__((address_space(1))) void*)g,
        (__attribute__((address_space(3))) void*)l,
        16, 0, 0);
}

// C[M,N] = A[M,K] @ Bt[N,K]^T (+ epilogue per MODE).
// 128x128x32 tile, 256 threads = 2x2 waves of 64x64. m97-style global_load_lds staging.
// z-batched: A += z*zsA, Bt += z*zsB, C index = z*zsC + row*ldc + z*zsCol + col.
template<int MODE>
__global__ __launch_bounds__(256)
void gemm_nt(const bf16_t* __restrict__ A, const bf16_t* __restrict__ Bt,
             bf16_t* __restrict__ Ob, float* __restrict__ Of,
             const float* __restrict__ bias, const float* __restrict__ res,
             const float* __restrict__ gates, int ge, int einit, float scale,
             int KC, int lda, int ldb, int ldc, int zsCol,
             long zsA, long zsB, long zsC)
{
    __shared__ bf16_t As[128 * 32];
    __shared__ bf16_t Bs[128 * 32];

    const int z = blockIdx.z;
    A  += (long)z * zsA;
    Bt += (long)z * zsB;

    const int tid  = threadIdx.x;
    const int wave = tid >> 6, lane = tid & 63;
    const int l16  = lane & 15, quad = lane >> 4;
    const int m0 = blockIdx.y * 128, n0 = blockIdx.x * 128;
    const int wr = wave >> 1, wc = wave & 1;

    // staging map: issue i (0/1), wave, lane -> row = i*64 + wave*16 + lane/4, col = (lane&3)*8
    const int srow = wave * 16 + (lane >> 2);
    const int scol = (lane & 3) * 8;
    const bf16_t* gA0 = A  + (long)(m0 + srow) * lda + scol;
    const bf16_t* gA1 = A  + (long)(m0 + 64 + srow) * lda + scol;
    const bf16_t* gB0 = Bt + (long)(n0 + srow) * ldb + scol;
    const bf16_t* gB1 = Bt + (long)(n0 + 64 + srow) * ldb + scol;
    bf16_t* lA0 = As + wave * 512;           // bytes: wave*1024
    bf16_t* lA1 = As + 2048 + wave * 512;    // + issue*4096B
    bf16_t* lB0 = Bs + wave * 512;
    bf16_t* lB1 = Bs + 2048 + wave * 512;

    f32x4 acc[4][4];
    #pragma unroll
    for (int i = 0; i < 4; i++)
        #pragma unroll
        for (int j = 0; j < 4; j++)
            acc[i][j] = f32x4{0.f, 0.f, 0.f, 0.f};

    for (int k0 = 0; k0 < KC; k0 += 32) {
        __syncthreads();                       // prior iter's ds_reads done
        gll16(gA0 + k0, lA0);
        gll16(gA1 + k0, lA1);
        gll16(gB0 + k0, lB0);
        gll16(gB1 + k0, lB1);
        __syncthreads();                       // drains vmcnt(0) + barrier

        bf16x8 af[4], bfr[4];
        #pragma unroll
        for (int i = 0; i < 4; i++)
            af[i] = *(const bf16x8*)&As[(wr * 64 + i * 16 + l16) * 32 + quad * 8];
        #pragma unroll
        for (int j = 0; j < 4; j++)
            bfr[j] = *(const bf16x8*)&Bs[(wc * 64 + j * 16 + l16) * 32 + quad * 8];

        #pragma unroll
        for (int i = 0; i < 4; i++)
            #pragma unroll
            for (int j = 0; j < 4; j++)
                acc[i][j] = __builtin_amdgcn_mfma_f32_16x16x32_bf16(af[i], bfr[j], acc[i][j], 0, 0, 0);
    }

    // C/D layout: col = lane&15, row = quad*4 + r (m89/m91-verified)
    #pragma unroll
    for (int i = 0; i < 4; i++) {
        const int row = m0 + wr * 64 + i * 16 + quad * 4;
        #pragma unroll
        for (int j = 0; j < 4; j++) {
            const int col = n0 + wc * 64 + j * 16 + l16;
            #pragma unroll
            for (int r = 0; r < 4; r++) {
                const int rr = row + r;
                const long idx = (long)z * zsC + (long)rr * ldc + (long)z * zsCol + col;
                const float vv = acc[i][j][r];
                if (MODE == M_SCORES) {
                    Of[idx] = vv * scale;
                } else if (MODE == M_PLAIN) {
                    Ob[idx] = (bf16_t)vv;
                } else if (MODE == M_BIAS) {
                    Ob[idx] = (bf16_t)(vv + bias[col]);
                } else if (MODE == M_BIAS_RES) {
                    Ob[idx] = (bf16_t)(vv + bias[col] + res[idx]);
                } else if (MODE == M_W1) {
                    float t = vv + bias[z * zsCol + col];
                    t = t > 0.f ? t : 0.f;
                    const float g = gates[rr * 8 + (ge >= 0 ? ge : z)];
                    Ob[idx] = (bf16_t)(t * g);
                } else if (MODE == M_PART) {
                    Of[idx] = einit ? vv : (Of[idx] + vv);
                }
            }
        }
    }
}

// out[z*sOut + c*ldOut + z*zcol + r] = bf16(in[z*sIn + r*C + c])
template<typename TIN>
__global__ __launch_bounds__(256)
void transpose_to_bf16(const TIN* __restrict__ in, bf16_t* __restrict__ out,
                       int C, int ldOut, int zcol, long sIn, long sOut)
{
    __shared__ bf16_t tile[32][33];
    const int z = blockIdx.z;
    in  += (long)z * sIn;
    out += (long)z * sOut + (long)z * zcol;
    const int c0 = blockIdx.x * 32, r0 = blockIdx.y * 32;
    const int tx = threadIdx.x, ty = threadIdx.y;
    #pragma unroll
    for (int i = ty; i < 32; i += 8)
        tile[i][tx] = (bf16_t)(float)in[(long)(r0 + i) * C + c0 + tx];
    __syncthreads();
    #pragma unroll
    for (int i = ty; i < 32; i += 8)
        out[(long)(c0 + i) * ldOut + r0 + tx] = tile[tx][i];
}

__global__ __launch_bounds__(256)
void convert_f32_bf16(const float* __restrict__ in, bf16_t* __restrict__ out, int n)
{
    const int i = (blockIdx.x * 256 + threadIdx.x) * 4;
    if (i >= n) return;
    const float4 v = *(const float4*)(in + i);
    bf16x4 o;
    o[0] = (bf16_t)v.x; o[1] = (bf16_t)v.y; o[2] = (bf16_t)v.z; o[3] = (bf16_t)v.w;
    *(bf16x4*)(out + i) = o;
}

__global__ __launch_bounds__(256)
void softmax_rows(const float* __restrict__ Sc, bf16_t* __restrict__ P)
{
    const int row = blockIdx.x, tid = threadIdx.x, wave = tid >> 6, lane = tid & 63;
    const float* sr = Sc + (long)row * 1024;
    bf16_t* pr = P + (long)row * 1024;
    float v[4];
    float mx = -3.4e38f;
    #pragma unroll
    for (int i = 0; i < 4; i++) { v[i] = sr[tid + 256 * i]; mx = fmaxf(mx, v[i]); }
    #pragma unroll
    for (int off = 32; off; off >>= 1) mx = fmaxf(mx, __shfl_down(mx, off));
    __shared__ float sm[4], ss[4];
    if (lane == 0) sm[wave] = mx;
    __syncthreads();
    mx = fmaxf(fmaxf(sm[0], sm[1]), fmaxf(sm[2], sm[3]));
    float sum = 0.f;
    #pragma unroll
    for (int i = 0; i < 4; i++) { v[i] = __expf(v[i] - mx); sum += v[i]; }
    #pragma unroll
    for (int off = 32; off; off >>= 1) sum += __shfl_down(sum, off);
    if (lane == 0) ss[wave] = sum;
    __syncthreads();
    const float inv = 1.f / (ss[0] + ss[1] + ss[2] + ss[3]);
    #pragma unroll
    for (int i = 0; i < 4; i++) pr[tid + 256 * i] = (bf16_t)(v[i] * inv);
}

__global__ __launch_bounds__(256)
void gates_kernel(const bf16_t* __restrict__ x2, const float* __restrict__ Wg,
                  const float* __restrict__ bg, float* __restrict__ gates, int H)
{
    const int wave = threadIdx.x >> 6, lane = threadIdx.x & 63;
    const int t = blockIdx.x * 4 + wave;
    const bf16_t* xr = x2 + (long)t * H;
    float acc[8] = {0.f, 0.f, 0.f, 0.f, 0.f, 0.f, 0.f, 0.f};
    for (int h = lane; h < H; h += 64) {
        const float xv = (float)xr[h];
        const float4 w0 = *(const float4*)(Wg + h * 8);
        const float4 w1 = *(const float4*)(Wg + h * 8 + 4);
        acc[0] += xv * w0.x; acc[1] += xv * w0.y; acc[2] += xv * w0.z; acc[3] += xv * w0.w;
        acc[4] += xv * w1.x; acc[5] += xv * w1.y; acc[6] += xv * w1.z; acc[7] += xv * w1.w;
    }
    #pragma unroll
    for (int off = 32; off; off >>= 1)
        #pragma unroll
        for (int e = 0; e < 8; e++) acc[e] += __shfl_down(acc[e], off);
    if (lane == 0) {
        float mx = -3.4e38f;
        #pragma unroll
        for (int e = 0; e < 8; e++) { acc[e] += bg[e]; mx = fmaxf(mx, acc[e]); }
        float s = 0.f;
        #pragma unroll
        for (int e = 0; e < 8; e++) { acc[e] = __expf(acc[e] - mx); s += acc[e]; }
        const float inv = 1.f / s;
        #pragma unroll
        for (int e = 0; e < 8; e++) gates[t * 8 + e] = acc[e] * inv;
    }
}

// out = x2 + yp0+yp1+yp2+yp3 + sum_e gates[t,e]*b2[e,h]
__global__ __launch_bounds__(256)
void final_add(const bf16_t* __restrict__ x2, const float* __restrict__ yp,
               const float* __restrict__ gates, const float* __restrict__ b2,
               float* __restrict__ out, long TH)
{
    const long i = (blockIdx.x * 256L + threadIdx.x) * 4;
    const int t = (int)(i >> 10), h = (int)(i & 1023);
    const float4 a0 = *(const float4*)(yp + i);
    const float4 a1 = *(const float4*)(yp + TH + i);
    const float4 a2 = *(const float4*)(yp + 2 * TH + i);
    const float4 a3 = *(const float4*)(yp + 3 * TH + i);
    float sx = a0.x + a1.x + a2.x + a3.x;
    float sy = a0.y + a1.y + a2.y + a3.y;
    float sz = a0.z + a1.z + a2.z + a3.z;
    float sw = a0.w + a1.w + a2.w + a3.w;
    const float* g = gates + t * 8;
    #pragma unroll
    for (int e = 0; e < 8; e++) {
        const float ge = g[e];
        const float4 b = *(const float4*)(b2 + e * 1024 + h);
        sx += ge * b.x; sy += ge * b.y; sz += ge * b.z; sw += ge * b.w;
    }
    const bf16x4 xv = *(const bf16x4*)(x2 + i);
    float4 o;
    o.x = (float)xv[0] + sx;
    o.y = (float)xv[1] + sy;
    o.z = (float)xv[2] + sz;
    o.w = (float)xv[3] + sw;
    *(float4*)(out + i) = o;
}

extern "C" void kernel_launch(void* const* d_in, const int* in_sizes, int n_in,
                              void* d_out, int out_size, void* d_ws, size_t ws_size,
                              hipStream_t stream)
{
    const int S = 1024, H = 1024, D = 4096, T = 4096;
    const long TH = (long)T * H;

    const float* x  = (const float*)d_in[0];
    const float* Wq = (const float*)d_in[1];
    const float* bq = (const float*)d_in[2];
    const float* Wk = (const float*)d_in[3];
    const float* bk = (const float*)d_in[4];
    const float* Wv = (const float*)d_in[5];
    const float* bv = (const float*)d_in[6];
    const float* Wo = (const float*)d_in[7];
    const float* bo = (const float*)d_in[8];
    const float* Wg = (const float*)d_in[9];
    const float* bg = (const float*)d_in[10];
    const float* W1 = (const float*)d_in[11];
    const float* b1 = (const float*)d_in[12];
    const float* W2 = (const float*)d_in[13];
    const float* b2 = (const float*)d_in[14];
    float* out = (float*)d_out;

    // Explicit layout, total 125,960,192 B (<= 134.5 MB proven in round 2).
    // yp occupies [0, 67.1MB); phase-A buffers alias inside it and are all
    // dead before the first M_PART write (e=0, einit covers all 4*TH floats).
    char* base = (char*)d_ws;
    float*  yp    = (float*) (base + 0);            // 4*TH*4 = 67,108,864
    bf16_t* x_bf  = (bf16_t*)(base + 0);            //  8,388,608  dead after V gemm
    bf16_t* WqT   = (bf16_t*)(base + 8388608);      //  2,097,152  dead after Q gemm
    bf16_t* WkT   = (bf16_t*)(base + 10485760);     //  2,097,152
    bf16_t* WvT   = (bf16_t*)(base + 12582912);     //  2,097,152
    bf16_t* WoT   = (bf16_t*)(base + 14680064);     //  2,097,152  dead after out-proj
    bf16_t* q     = (bf16_t*)(base + 16777216);     //  8,388,608  (attn) dead after attn@v
    bf16_t* k     = (bf16_t*)(base + 25165824);     //  8,388,608  (a) dead after out-proj
    bf16_t* vT    = (bf16_t*)(base + 33554432);     //  8,388,608  dead after attn@v
    float*  scores= (float*) (base + 41943040);     // 16,777,216  dead after softmax -> ends 58,720,256
    bf16_t* v     = (bf16_t*)(base + 67108864);     //  8,388,608  (x2) live to end
    float*  gates = (float*) (base + 75497472);     //    131,072
    bf16_t* W1T   = (bf16_t*)(base + 75628544);     //  8,388,608
    bf16_t* W2T   = (bf16_t*)(base + 84017152);     //  8,388,608
    bf16_t* hmid  = (bf16_t*)(base + 92405760);     // 33,554,432 -> ends 125,960,192
    bf16_t* attn = q;
    bf16_t* a    = k;
    bf16_t* x2   = v;

    const dim3 tb(32, 8);

    convert_f32_bf16<<<4096, 256, 0, stream>>>(x, x_bf, T * H);
    transpose_to_bf16<float><<<dim3(32, 32, 1), tb, 0, stream>>>(Wq, WqT, H, H, 0, 0, 0);
    transpose_to_bf16<float><<<dim3(32, 32, 1), tb, 0, stream>>>(Wk, WkT, H, H, 0, 0, 0);
    transpose_to_bf16<float><<<dim3(32, 32, 1), tb, 0, stream>>>(Wv, WvT, H, H, 0, 0, 0);
    transpose_to_bf16<float><<<dim3(32, 32, 1), tb, 0, stream>>>(Wo, WoT, H, H, 0, 0, 0);

    // --- attention ---
    gemm_nt<M_BIAS><<<dim3(8, 32, 1), 256, 0, stream>>>(x_bf, WqT, q, nullptr, bq, nullptr, nullptr, -1, 0, 0.f,
                                                        H, H, H, H, 0, 0, 0, 0);
    gemm_nt<M_BIAS><<<dim3(8, 32, 1), 256, 0, stream>>>(x_bf, WkT, k, nullptr, bk, nullptr, nullptr, -1, 0, 0.f,
                                                        H, H, H, H, 0, 0, 0, 0);
    gemm_nt<M_BIAS><<<dim3(8, 32, 1), 256, 0, stream>>>(x_bf, WvT, v, nullptr, bv, nullptr, nullptr, -1, 0, 0.f,
                                                        H, H, H, H, 0, 0, 0, 0);
    transpose_to_bf16<bf16_t><<<dim3(32, 32, 4), tb, 0, stream>>>(v, vT, H, S, 0, (long)S * H, (long)H * S);

    gemm_nt<M_SCORES><<<dim3(8, 8, 4), 256, 0, stream>>>(q, k, nullptr, scores, nullptr, nullptr, nullptr, -1, 0, 0.03125f,
                                                         H, H, H, S, 0, (long)S * H, (long)S * H, (long)S * S);
    softmax_rows<<<4096, 256, 0, stream>>>(scores, attn);

    gemm_nt<M_PLAIN><<<dim3(8, 8, 4), 256, 0, stream>>>(attn, vT, a, nullptr, nullptr, nullptr, nullptr, -1, 0, 0.f,
                                                        S, S, S, H, 0, (long)S * S, (long)H * S, (long)S * H);
    gemm_nt<M_BIAS_RES><<<dim3(8, 32, 1), 256, 0, stream>>>(a, WoT, x2, nullptr, bo, x, nullptr, -1, 0, 0.f,
                                                            H, H, H, H, 0, 0, 0, 0);

    // --- soft-MoE: gates folded into W1 epilogue; b2 folded into final_add ---
    gates_kernel<<<1024, 256, 0, stream>>>(x2, Wg, bg, gates, H);

    for (int e = 0; e < 8; e++) {
        transpose_to_bf16<float><<<dim3(128, 32, 1), tb, 0, stream>>>(W1 + (long)e * H * D, W1T, D, H, 0, 0, 0);
        gemm_nt<M_W1><<<dim3(32, 32, 1), 256, 0, stream>>>(x2, W1T, hmid, nullptr, b1 + (long)e * D, nullptr, gates, e, 0, 0.f,
                                                           H, H, H, D, 0, 0, 0, 0);
        transpose_to_bf16<float><<<dim3(32, 128, 1), tb, 0, stream>>>(W2 + (long)e * D * H, W2T, H, D, 0, 0, 0);
        // split-K=4 (z = K-chunk of 1024) -> 1024 blocks; partials contiguous at yp + z*TH
        gemm_nt<M_PART><<<dim3(8, 32, 4), 256, 0, stream>>>(hmid, W2T, nullptr, yp, nullptr, nullptr, nullptr, -1, (e == 0) ? 1 : 0, 0.f,
                                                            1024, D, D, H, 0, 1024, 1024, TH);
    }

    final_add<<<4096, 256, 0, stream>>>(x2, yp, gates, b2, out, TH);
}